// Round 5
// baseline (109.308 us; speedup 1.0000x reference)
//
#include <hip/hip_runtime.h>
#include <math.h>

#define NPTS 8192
#define NB 4
#define BLK 256
#define Q 16             // queries per thread
#define TILE 256         // ref points staged per tile (== BLK, == seg_len at NSEG=32)
#define QCHUNKS (NPTS / (BLK * Q))   // 2

typedef float v2f __attribute__((ext_vector_type(2)));

#if __has_builtin(__builtin_elementwise_fma)
#define VFMA(a, b, c) __builtin_elementwise_fma((a), (b), (c))
#else
static __device__ inline v2f VFMA(v2f a, v2f b, v2f c) {
    v2f r; r.x = fmaf(a.x, b.x, c.x); r.y = fmaf(a.y, b.y, c.y); return r;
}
#endif

#define REPEAT16(M) M(0) M(1) M(2) M(3) M(4) M(5) M(6) M(7) \
                    M(8) M(9) M(10) M(11) M(12) M(13) M(14) M(15)

// Kernel 1: partial[bd][seg][q] = min over refs in segment of (|r|^2 - 2 q.r)
// (|q|^2 added in kernel 2; min commutes with +|q|^2 and the clamp.)
// Packed-fp32 inner loop: refs processed in pairs via v_pk_fma_f32
// (3 pk_fma + 1 min3 per query per ref-PAIR -> 2 VALU/pair vs 4 scalar).
template <int NSEG>
__global__ __launch_bounds__(BLK) void chamfer_partial(
    const float* __restrict__ tmpl, const float* __restrict__ src,
    float* __restrict__ partial)
{
    // pair p holds refs (2p, 2p+1):
    //   ldsA[p] = (-2x0, -2x1, -2y0, -2y1)
    //   ldsB[p] = (-2z0, -2z1,  w0,   w1)   w = |r|^2
    __shared__ float4 ldsA[TILE / 2];
    __shared__ float4 ldsB[TILE / 2];

    const int bd  = blockIdx.z;          // 0..7 = b*2 + dir
    const int b   = bd >> 1;
    const int dir = bd & 1;
    const float* qp = (dir ? src : tmpl) + (size_t)b * NPTS * 3;
    const float* rp = (dir ? tmpl : src) + (size_t)b * NPTS * 3;
    const int tid   = threadIdx.x;
    const int qbase = blockIdx.x * (BLK * Q);

#define DECL(i) v2f qx##i, qy##i, qz##i; float mn##i = 3.4e38f;
    REPEAT16(DECL)
#undef DECL
#define LOADQ(i) { const int qi = qbase + (i) * BLK + tid;              \
                   const float x = qp[3 * qi + 0];                      \
                   const float y = qp[3 * qi + 1];                      \
                   const float z = qp[3 * qi + 2];                      \
                   qx##i = (v2f){x, x};                                 \
                   qy##i = (v2f){y, y};                                 \
                   qz##i = (v2f){z, z}; }
    REPEAT16(LOADQ)
#undef LOADQ

    const int seg_len   = NPTS / NSEG;   // compile-time (256 at NSEG=32)
    const int seg_start = blockIdx.y * seg_len;
    for (int ts = 0; ts < seg_len; ts += TILE) {
        __syncthreads();
        {
            const int ri = seg_start + ts + tid;   // TILE == BLK: 1 ref/thread
            const float rx = rp[3 * ri + 0];
            const float ry = rp[3 * ri + 1];
            const float rz = rp[3 * ri + 2];
            float* pa = (float*)&ldsA[tid >> 1];
            float* pb = (float*)&ldsB[tid >> 1];
            const int h = tid & 1;
            pa[h]     = -2.f * rx;
            pa[2 + h] = -2.f * ry;
            pb[h]     = -2.f * rz;
            pb[2 + h] = rx * rx + ry * ry + rz * rz;
        }
        __syncthreads();
#pragma unroll 2
        for (int p = 0; p < TILE / 2; p++) {
            const float4 A = ldsA[p];
            const float4 B = ldsB[p];
            const v2f rx01 = (v2f){A.x, A.y};
            const v2f ry01 = (v2f){A.z, A.w};
            const v2f rz01 = (v2f){B.x, B.y};
            const v2f rw01 = (v2f){B.z, B.w};
            v2f t;
#define STEP(i) t = VFMA(qx##i, rx01, rw01);            \
                t = VFMA(qy##i, ry01, t);               \
                t = VFMA(qz##i, rz01, t);               \
                mn##i = fminf(mn##i, fminf(t.x, t.y));  /* -> v_min3_f32 */
            REPEAT16(STEP)
#undef STEP
        }
    }

    const size_t base = ((size_t)bd * NSEG + blockIdx.y) * NPTS + qbase + tid;
#define STORE(i) partial[base + (size_t)(i) * BLK] = mn##i;
    REPEAT16(STORE)
#undef STORE
}

// Kernel 2: combine segment partials, add |q|^2, clamp, sqrt, global mean.
template <int NSEG>
__global__ __launch_bounds__(BLK) void chamfer_reduce(
    const float* __restrict__ tmpl, const float* __restrict__ src,
    const float* __restrict__ partial, float* __restrict__ out)
{
    const int t  = blockIdx.x * BLK + threadIdx.x;  // 0 .. 8*NPTS-1
    const int bd = t >> 13;                         // / NPTS
    const int qi = t & (NPTS - 1);
    const int b  = bd >> 1;
    const int dir = bd & 1;
    const float* qp = (dir ? src : tmpl) + (size_t)b * NPTS * 3;

    float v[NSEG];
#pragma unroll
    for (int s = 0; s < NSEG; s++)
        v[s] = partial[((size_t)bd * NSEG + s) * NPTS + qi];
#pragma unroll
    for (int w = NSEG; w > 1; w >>= 1)
#pragma unroll
        for (int s = 0; s < w / 2; s++)
            v[s] = fminf(v[s], v[s + w / 2]);

    const float qx = qp[3 * qi + 0];
    const float qy = qp[3 * qi + 1];
    const float qz = qp[3 * qi + 2];
    const float sq = qx * qx + qy * qy + qz * qz;

    float val = sqrtf(fmaxf(sq + v[0], 0.f));

    // wave reduction (64 lanes)
#pragma unroll
    for (int off = 32; off > 0; off >>= 1)
        val += __shfl_down(val, off, 64);

    __shared__ float wsum[BLK / 64];
    const int lane = threadIdx.x & 63;
    const int wid  = threadIdx.x >> 6;
    if (lane == 0) wsum[wid] = val;
    __syncthreads();
    if (threadIdx.x == 0) {
        float s = 0.f;
#pragma unroll
        for (int w = 0; w < BLK / 64; w++) s += wsum[w];
        // mean over N (8192) * avg 2 dirs * mean 4 batches = /65536
        atomicAdd(out, s * (1.0f / 65536.0f));
    }
}

extern "C" void kernel_launch(void* const* d_in, const int* in_sizes, int n_in,
                              void* d_out, int out_size, void* d_ws, size_t ws_size,
                              hipStream_t stream) {
    const float* tmpl = (const float*)d_in[0];
    const float* src  = (const float*)d_in[1];
    float* out     = (float*)d_out;
    float* partial = (float*)d_ws;

    // choose nseg (power of 2, <=32) to fit workspace: 8*nseg*NPTS*4 bytes
    int nseg = 32;
    while (nseg > 1 && (size_t)8 * nseg * NPTS * sizeof(float) > ws_size)
        nseg >>= 1;

    hipMemsetAsync(d_out, 0, sizeof(float), stream);

    const int g2 = (2 * NB * NPTS) / BLK;
    switch (nseg) {
    case 32: {
        dim3 g1(QCHUNKS, 32, 2 * NB);
        chamfer_partial<32><<<g1, BLK, 0, stream>>>(tmpl, src, partial);
        chamfer_reduce<32><<<g2, BLK, 0, stream>>>(tmpl, src, partial, out);
        break;
    }
    case 16: {
        dim3 g1(QCHUNKS, 16, 2 * NB);
        chamfer_partial<16><<<g1, BLK, 0, stream>>>(tmpl, src, partial);
        chamfer_reduce<16><<<g2, BLK, 0, stream>>>(tmpl, src, partial, out);
        break;
    }
    case 8: {
        dim3 g1(QCHUNKS, 8, 2 * NB);
        chamfer_partial<8><<<g1, BLK, 0, stream>>>(tmpl, src, partial);
        chamfer_reduce<8><<<g2, BLK, 0, stream>>>(tmpl, src, partial, out);
        break;
    }
    case 4: {
        dim3 g1(QCHUNKS, 4, 2 * NB);
        chamfer_partial<4><<<g1, BLK, 0, stream>>>(tmpl, src, partial);
        chamfer_reduce<4><<<g2, BLK, 0, stream>>>(tmpl, src, partial, out);
        break;
    }
    case 2: {
        dim3 g1(QCHUNKS, 2, 2 * NB);
        chamfer_partial<2><<<g1, BLK, 0, stream>>>(tmpl, src, partial);
        chamfer_reduce<2><<<g2, BLK, 0, stream>>>(tmpl, src, partial, out);
        break;
    }
    default: {
        dim3 g1(QCHUNKS, 1, 2 * NB);
        chamfer_partial<1><<<g1, BLK, 0, stream>>>(tmpl, src, partial);
        chamfer_reduce<1><<<g2, BLK, 0, stream>>>(tmpl, src, partial, out);
        break;
    }
    }
}

// Round 6
// 108.738 us; speedup vs baseline: 1.0052x; 1.0052x over previous
//
#include <hip/hip_runtime.h>
#include <math.h>

#define NPTS 8192
#define NB 4
#define BLK 256
#define Q 8              // queries per thread
#define TILE 256         // ref points staged per tile (== BLK)
#define QCHUNKS (NPTS / (BLK * Q))   // 4

typedef float v2f __attribute__((ext_vector_type(2)));

#if __has_builtin(__builtin_elementwise_fma)
#define VFMA(a, b, c) __builtin_elementwise_fma((a), (b), (c))
#else
static __device__ inline v2f VFMA(v2f a, v2f b, v2f c) {
    v2f r; r.x = fmaf(a.x, b.x, c.x); r.y = fmaf(a.y, b.y, c.y); return r;
}
#endif

#define REPEAT8(M) M(0) M(1) M(2) M(3) M(4) M(5) M(6) M(7)

// Kernel 1: partial[bd][seg][q] = min over refs in segment of (|r|^2 - 2 q.r)
// (|q|^2 added in kernel 2; min commutes with +|q|^2 and the clamp.)
// Inner loop: v_pk_fma_f32 pairs (3 pk_fma + 1 v_min3 per query per ref-PAIR
// = 2 VALU/pair). Round 5 proved the packed codegen (VALU-busy 31 us) but at
// 2 waves/SIMD latency was exposed; this build runs 1024 blocks = 4/SIMD.
template <int NSEG>
__global__ __launch_bounds__(BLK) void chamfer_partial(
    const float* __restrict__ tmpl, const float* __restrict__ src,
    float* __restrict__ partial)
{
    // pair p holds refs (2p, 2p+1):
    //   ldsA[p] = (-2x0, -2x1, -2y0, -2y1)
    //   ldsB[p] = (-2z0, -2z1,  w0,   w1)   w = |r|^2
    __shared__ float4 ldsA[TILE / 2];
    __shared__ float4 ldsB[TILE / 2];

    const int bd  = blockIdx.z;          // 0..7 = b*2 + dir
    const int b   = bd >> 1;
    const int dir = bd & 1;
    const float* qp = (dir ? src : tmpl) + (size_t)b * NPTS * 3;
    const float* rp = (dir ? tmpl : src) + (size_t)b * NPTS * 3;
    const int tid   = threadIdx.x;
    const int qbase = blockIdx.x * (BLK * Q);

#define DECL(i) v2f qx##i, qy##i, qz##i; float mn##i = 3.4e38f;
    REPEAT8(DECL)
#undef DECL
#define LOADQ(i) { const int qi = qbase + (i) * BLK + tid;              \
                   const float x = qp[3 * qi + 0];                      \
                   const float y = qp[3 * qi + 1];                      \
                   const float z = qp[3 * qi + 2];                      \
                   qx##i = (v2f){x, x};                                 \
                   qy##i = (v2f){y, y};                                 \
                   qz##i = (v2f){z, z}; }
    REPEAT8(LOADQ)
#undef LOADQ

    const int seg_len   = NPTS / NSEG;   // compile-time (256 at NSEG=32)
    const int seg_start = blockIdx.y * seg_len;
    for (int ts = 0; ts < seg_len; ts += TILE) {
        __syncthreads();
        {
            const int ri = seg_start + ts + tid;   // TILE == BLK: 1 ref/thread
            const float rx = rp[3 * ri + 0];
            const float ry = rp[3 * ri + 1];
            const float rz = rp[3 * ri + 2];
            float* pa = (float*)&ldsA[tid >> 1];
            float* pb = (float*)&ldsB[tid >> 1];
            const int h = tid & 1;
            pa[h]     = -2.f * rx;
            pa[2 + h] = -2.f * ry;
            pb[h]     = -2.f * rz;
            pb[2 + h] = rx * rx + ry * ry + rz * rz;
        }
        __syncthreads();
#pragma unroll 4
        for (int p = 0; p < TILE / 2; p++) {
            const float4 A = ldsA[p];
            const float4 B = ldsB[p];
            const v2f rx01 = (v2f){A.x, A.y};
            const v2f ry01 = (v2f){A.z, A.w};
            const v2f rz01 = (v2f){B.x, B.y};
            const v2f rw01 = (v2f){B.z, B.w};
            v2f t;
#define STEP(i) t = VFMA(qx##i, rx01, rw01);            \
                t = VFMA(qy##i, ry01, t);               \
                t = VFMA(qz##i, rz01, t);               \
                mn##i = fminf(mn##i, fminf(t.x, t.y));  /* -> v_min3_f32 */
            REPEAT8(STEP)
#undef STEP
        }
    }

    const size_t base = ((size_t)bd * NSEG + blockIdx.y) * NPTS + qbase + tid;
#define STORE(i) partial[base + (size_t)(i) * BLK] = mn##i;
    REPEAT8(STORE)
#undef STORE
}

// Kernel 2: combine segment partials, add |q|^2, clamp, sqrt, global mean.
template <int NSEG>
__global__ __launch_bounds__(BLK) void chamfer_reduce(
    const float* __restrict__ tmpl, const float* __restrict__ src,
    const float* __restrict__ partial, float* __restrict__ out)
{
    const int t  = blockIdx.x * BLK + threadIdx.x;  // 0 .. 8*NPTS-1
    const int bd = t >> 13;                         // / NPTS
    const int qi = t & (NPTS - 1);
    const int b  = bd >> 1;
    const int dir = bd & 1;
    const float* qp = (dir ? src : tmpl) + (size_t)b * NPTS * 3;

    float v[NSEG];
#pragma unroll
    for (int s = 0; s < NSEG; s++)
        v[s] = partial[((size_t)bd * NSEG + s) * NPTS + qi];
#pragma unroll
    for (int w = NSEG; w > 1; w >>= 1)
#pragma unroll
        for (int s = 0; s < w / 2; s++)
            v[s] = fminf(v[s], v[s + w / 2]);

    const float qx = qp[3 * qi + 0];
    const float qy = qp[3 * qi + 1];
    const float qz = qp[3 * qi + 2];
    const float sq = qx * qx + qy * qy + qz * qz;

    float val = sqrtf(fmaxf(sq + v[0], 0.f));

    // wave reduction (64 lanes)
#pragma unroll
    for (int off = 32; off > 0; off >>= 1)
        val += __shfl_down(val, off, 64);

    __shared__ float wsum[BLK / 64];
    const int lane = threadIdx.x & 63;
    const int wid  = threadIdx.x >> 6;
    if (lane == 0) wsum[wid] = val;
    __syncthreads();
    if (threadIdx.x == 0) {
        float s = 0.f;
#pragma unroll
        for (int w = 0; w < BLK / 64; w++) s += wsum[w];
        // mean over N (8192) * avg 2 dirs * mean 4 batches = /65536
        atomicAdd(out, s * (1.0f / 65536.0f));
    }
}

extern "C" void kernel_launch(void* const* d_in, const int* in_sizes, int n_in,
                              void* d_out, int out_size, void* d_ws, size_t ws_size,
                              hipStream_t stream) {
    const float* tmpl = (const float*)d_in[0];
    const float* src  = (const float*)d_in[1];
    float* out     = (float*)d_out;
    float* partial = (float*)d_ws;

    // choose nseg (power of 2, <=32) to fit workspace: 8*nseg*NPTS*4 bytes
    int nseg = 32;
    while (nseg > 1 && (size_t)8 * nseg * NPTS * sizeof(float) > ws_size)
        nseg >>= 1;

    hipMemsetAsync(d_out, 0, sizeof(float), stream);

    const int g2 = (2 * NB * NPTS) / BLK;
    switch (nseg) {
    case 32: {
        dim3 g1(QCHUNKS, 32, 2 * NB);
        chamfer_partial<32><<<g1, BLK, 0, stream>>>(tmpl, src, partial);
        chamfer_reduce<32><<<g2, BLK, 0, stream>>>(tmpl, src, partial, out);
        break;
    }
    case 16: {
        dim3 g1(QCHUNKS, 16, 2 * NB);
        chamfer_partial<16><<<g1, BLK, 0, stream>>>(tmpl, src, partial);
        chamfer_reduce<16><<<g2, BLK, 0, stream>>>(tmpl, src, partial, out);
        break;
    }
    case 8: {
        dim3 g1(QCHUNKS, 8, 2 * NB);
        chamfer_partial<8><<<g1, BLK, 0, stream>>>(tmpl, src, partial);
        chamfer_reduce<8><<<g2, BLK, 0, stream>>>(tmpl, src, partial, out);
        break;
    }
    case 4: {
        dim3 g1(QCHUNKS, 4, 2 * NB);
        chamfer_partial<4><<<g1, BLK, 0, stream>>>(tmpl, src, partial);
        chamfer_reduce<4><<<g2, BLK, 0, stream>>>(tmpl, src, partial, out);
        break;
    }
    case 2: {
        dim3 g1(QCHUNKS, 2, 2 * NB);
        chamfer_partial<2><<<g1, BLK, 0, stream>>>(tmpl, src, partial);
        chamfer_reduce<2><<<g2, BLK, 0, stream>>>(tmpl, src, partial, out);
        break;
    }
    default: {
        dim3 g1(QCHUNKS, 1, 2 * NB);
        chamfer_partial<1><<<g1, BLK, 0, stream>>>(tmpl, src, partial);
        chamfer_reduce<1><<<g2, BLK, 0, stream>>>(tmpl, src, partial, out);
        break;
    }
    }
}